// Round 10
// baseline (33.511 us; speedup 1.0000x reference)
//
#include <hip/hip_runtime.h>

typedef __attribute__((ext_vector_type(8)))  short short8;
typedef __attribute__((ext_vector_type(16))) float f32x16;

#define NPTS 2048
#define BATCH 32
#define NUM_CLASSES 6
#define BF16_ONE ((short)0x3F80)

// ws byte offsets
#define BIMG_OFF 0                      // [64][2048][32B] = 4 MB
#define AIMG_OFF (4u << 20)             // [64][2048][2][16B] = 4 MB
#define PMIN_OFF (8u << 20)             // [1024][256] float = 1 MB
#define PART_OFF (9u << 20)             // [512] float

__device__ __forceinline__ unsigned short f2bf(float x) {
    union { float f; unsigned u; } v; v.f = x;
    unsigned r = v.u + 0x7FFF + ((v.u >> 16) & 1);   // RNE to bf16
    return (unsigned short)(r >> 16);
}
__device__ __forceinline__ float bf2f(unsigned short h) {
    union { unsigned u; float f; } v; v.u = ((unsigned)h) << 16; return v.f;
}
template<int CTRL>
__device__ __forceinline__ float dpp_ror_min(float v) {
    union { float f; int i; } a, r;
    a.f = v;
    r.i = __builtin_amdgcn_update_dpp(a.i, a.i, CTRL, 0xF, 0xF, false);
    return fminf(v, r.f);
}
__device__ __forceinline__ float swz_xor16_min(float v) {
    union { float f; int i; } a, s;
    a.f = v; s.i = __builtin_amdgcn_ds_swizzle(a.i, 0x401F);
    return fminf(v, s.f);
}
__device__ __forceinline__ void gload_lds16(const char* g, char* l) {
    __builtin_amdgcn_global_load_lds(
        (__attribute__((address_space(1))) void*)(g),
        (__attribute__((address_space(3))) void*)(l), 16, 0, 0);
}

// K-slot plan (K=16, absmax-0 verified R3-R9): D = a2 + b2 - 2 a.b
//  k0-2: A=ah B=-2bh | k3-5: A=al B=-2bh | k6-8: A=ah B=-2bl
//  k9: A=1 B=b2h | k10: A=1 B=b2l | k11: A=a2h B=1 | k12: A=a2l B=1 | rest 0
__device__ __forceinline__ void stage_cand(char* dst, float bx, float by, float bz) {
    float m2x = -2.f*bx, m2y = -2.f*by, m2z = -2.f*bz;
    unsigned short hx = f2bf(m2x), hy = f2bf(m2y), hz = f2bf(m2z);
    unsigned short lx = f2bf(m2x - bf2f(hx));
    unsigned short ly = f2bf(m2y - bf2f(hy));
    unsigned short lz = f2bf(m2z - bf2f(hz));
    float b2 = fmaf(bx,bx, fmaf(by,by, bz*bz));
    unsigned short b2h = f2bf(b2);
    unsigned short b2l = f2bf(b2 - bf2f(b2h));
    short8 kg0 = { (short)hx,(short)hy,(short)hz,(short)hx,(short)hy,(short)hz,(short)lx,(short)ly };
    short8 kg1 = { (short)lz,(short)b2h,(short)b2l, BF16_ONE, BF16_ONE, 0,0,0 };
    *(short8*)(dst)      = kg0;
    *(short8*)(dst + 16) = kg1;
}
__device__ __forceinline__ void stage_query(char* dst, float x, float y, float z) {
    unsigned short hx = f2bf(x), hy = f2bf(y), hz = f2bf(z);
    unsigned short lx = f2bf(x - bf2f(hx));
    unsigned short ly = f2bf(y - bf2f(hy));
    unsigned short lz = f2bf(z - bf2f(hz));
    float a2 = fmaf(x,x, fmaf(y,y, z*z));
    unsigned short a2h = f2bf(a2);
    unsigned short a2l = f2bf(a2 - bf2f(a2h));
    short8 f0 = { (short)hx,(short)hy,(short)hz,(short)lx,(short)ly,(short)lz,(short)hx,(short)hy };
    short8 f1 = { (short)hz, BF16_ONE, BF16_ONE, (short)a2h,(short)a2l, 0,0,0 };
    *(short8*)(dst)      = f0;   // lh=0 variant
    *(short8*)(dst + 16) = f1;   // lh=1 variant
}

// ---- kernel 0: one-time conversion into frag images ------------------------
__global__ __launch_bounds__(256) void prep_kernel(
    const float* __restrict__ inst, const float* __restrict__ model,
    char* __restrict__ ws)
{
    const int p = blockIdx.x;                 // 256 blocks
    const int dir = p >> 7, batch = (p >> 2) & 31, quarter = p & 3;
    const int dirbatch = dir * BATCH + batch;
    const int tid = threadIdx.x;

    const float* Qsrc = dir ? model : inst;   // A side (queries)
    const float* Csrc = dir ? inst  : model;  // B side (candidates)

    {   // 2 candidates -> B-frag image
        const int c0 = quarter * 512 + tid * 2;
        const float* src = Csrc + (size_t)batch * NPTS * 3 + (size_t)c0 * 3;
        float2 p0 = *(const float2*)(src);
        float2 p1 = *(const float2*)(src + 2);
        float2 p2 = *(const float2*)(src + 4);
        char* dst = ws + BIMG_OFF + ((size_t)dirbatch * NPTS + c0) * 32;
        stage_cand(dst,      p0.x, p0.y, p1.x);
        stage_cand(dst + 32, p1.y, p2.x, p2.y);
    }
    {   // 2 queries -> A-frag image
        const int q0 = quarter * 512 + tid * 2;
        const float* src = Qsrc + (size_t)batch * NPTS * 3 + (size_t)q0 * 3;
        float2 p0 = *(const float2*)(src);
        float2 p1 = *(const float2*)(src + 2);
        float2 p2 = *(const float2*)(src + 4);
        char* dst = ws + AIMG_OFF + ((size_t)dirbatch * NPTS + q0) * 32;
        stage_query(dst,      p0.x, p0.y, p1.x);
        stage_query(dst + 32, p1.y, p2.x, p2.y);
    }
}

// ---- kernel 1: MFMA chamfer over preformatted frags ------------------------
// grid 1024: b -> cc(&1), qc(>>1 &7), batch(>>4 &31), dir(>>9).
// Block: 256 queries vs 1024 candidates; per-query min -> pmin[b][256].
__global__ __launch_bounds__(256, 4) void chamfer_pass1(
    const char* __restrict__ bimg, const char* __restrict__ aimg,
    float* __restrict__ pmin)
{
    __shared__ __align__(16) char cands[32768];
    __shared__ float out_s[256];

    const int b = blockIdx.x;
    const int cc = b & 1, qc = (b >> 1) & 7, batch = (b >> 4) & 31, dir = b >> 9;
    const int dirbatch = dir * BATCH + batch;
    const int tid = threadIdx.x, lane = tid & 63, wid = tid >> 6;
    const int lh = lane >> 5, lr = lane & 31;

    // async-stage 32 KB preformatted B-frags (no VALU, no reg round-trip)
    {
        const char* g = bimg + ((size_t)dirbatch * NPTS + (size_t)cc * 1024) * 32
                        + wid * 8192 + lane * 16;
        char* l = cands + wid * 8192;          // wave-uniform dest
        #pragma unroll
        for (int j = 0; j < 8; ++j)
            gload_lds16(g + j * 1024, l + j * 1024);
    }

    // preformatted A-frags: queries wid*64+lr (+32), variant lh
    const char* asrc = aimg
        + ((size_t)dirbatch * NPTS + (size_t)qc * 256 + wid * 64 + lr) * 32 + lh * 16;
    short8 af0 = *(const short8*)(asrc);
    short8 af1 = *(const short8*)(asrc + 1024);   // +32 queries

    __syncthreads();   // vmcnt(0) drained at barrier -> LDS ready

    f32x16 mn, mn2, zero16;
    #pragma unroll
    for (int r = 0; r < 16; ++r) { mn[r] = 3.4e38f; mn2[r] = 3.4e38f; zero16[r] = 0.f; }

    int boff = lr * 32 + lh * 16;
    for (int t = 0; t < 16; ++t) {
        short8 b0 = *(const short8*)(cands + boff);
        short8 b1 = *(const short8*)(cands + boff + 1024);
        boff += 2048;
        f32x16 t0 = __builtin_amdgcn_mfma_f32_32x32x16_bf16(af0, b0, zero16, 0,0,0);
        f32x16 t1 = __builtin_amdgcn_mfma_f32_32x32x16_bf16(af0, b1, zero16, 0,0,0);
        #pragma unroll
        for (int r = 0; r < 16; ++r) mn[r] = fminf(mn[r], fminf(t0[r], t1[r]));   // v_min3
        f32x16 u0 = __builtin_amdgcn_mfma_f32_32x32x16_bf16(af1, b0, zero16, 0,0,0);
        f32x16 u1 = __builtin_amdgcn_mfma_f32_32x32x16_bf16(af1, b1, zero16, 0,0,0);
        #pragma unroll
        for (int r = 0; r < 16; ++r) mn2[r] = fminf(mn2[r], fminf(u0[r], u1[r]));
    }

    // col-min across 32 cand-lanes: 4 DPP row_ror (VALU) + 1 xor16 swizzle
    // D layout: col = lane&31, row = (r&3) + 8*(r>>2) + 4*lh
    #pragma unroll
    for (int r = 0; r < 16; ++r) {
        float v = mn[r];
        v = dpp_ror_min<0x121>(v);
        v = dpp_ror_min<0x122>(v);
        v = dpp_ror_min<0x124>(v);
        v = dpp_ror_min<0x128>(v);
        v = swz_xor16_min(v);
        if (lr == 0) out_s[wid*64 + ((r&3) + 8*(r>>2) + 4*lh)] = v;
        float w = mn2[r];
        w = dpp_ror_min<0x121>(w);
        w = dpp_ror_min<0x122>(w);
        w = dpp_ror_min<0x124>(w);
        w = dpp_ror_min<0x128>(w);
        w = swz_xor16_min(w);
        if (lr == 0) out_s[wid*64 + 32 + ((r&3) + 8*(r>>2) + 4*lh)] = w;
    }
    __syncthreads();
    pmin[(size_t)b * 256 + tid] = out_s[tid];   // coalesced
}

// ---- kernel 2: min across the 2 cc-chunks, sum 256 queries -----------------
__global__ __launch_bounds__(256) void combine_kernel(
    const float* __restrict__ pmin, float* __restrict__ partial)
{
    const int g   = blockIdx.x;    // 0..511 = (dir,batch,qc)
    const int tid = threadIdx.x;
    const float* p0 = pmin + (size_t)(g * 2) * 256;
    float s = fminf(p0[tid], p0[256 + tid]);
    #pragma unroll
    for (int o = 32; o > 0; o >>= 1) s += __shfl_down(s, o, 64);
    __shared__ float wsum[4];
    const int lane = tid & 63, wid = tid >> 6;
    if (lane == 0) wsum[wid] = s;
    __syncthreads();
    if (tid == 0) partial[g] = (wsum[0] + wsum[1]) + (wsum[2] + wsum[3]);
}

// ---- kernel 3: 512-sum + cross-entropy + output ----------------------------
__global__ __launch_bounds__(256) void finalize_kernel(
    const float* __restrict__ partial, const float* __restrict__ pred,
    const int* __restrict__ gt, float* __restrict__ out)
{
    __shared__ float s_ce[BATCH];
    __shared__ float wsum[4];
    const int tid = threadIdx.x;

    float v = partial[tid] + partial[tid + 256];
    #pragma unroll
    for (int o = 32; o > 0; o >>= 1) v += __shfl_down(v, o, 64);
    const int lane = tid & 63, wid = tid >> 6;
    if (lane == 0) wsum[wid] = v;

    if (tid < BATCH) {
        const float* row = pred + tid * NUM_CLASSES;
        float mx = row[0];
        #pragma unroll
        for (int c = 1; c < NUM_CLASSES; ++c) mx = fmaxf(mx, row[c]);
        float se = 0.f;
        #pragma unroll
        for (int c = 0; c < NUM_CLASSES; ++c) se += __expf(row[c] - mx);
        const int lbl = gt[tid];
        s_ce[tid] = -(row[lbl] - mx - __logf(se));
    }
    __syncthreads();

    if (tid == 0) {
        float cd = ((wsum[0] + wsum[1]) + (wsum[2] + wsum[3])) / (float)(BATCH * NPTS);
        float ce = 0.f;
        for (int i = 0; i < BATCH; ++i) ce += s_ce[i];
        ce /= (float)BATCH;
        out[0] = 5.f * cd + ce;
        out[1] = cd;
        out[2] = ce;
    }
}

extern "C" void kernel_launch(void* const* d_in, const int* in_sizes, int n_in,
                              void* d_out, int out_size, void* d_ws, size_t ws_size,
                              hipStream_t stream) {
    const float* inst  = (const float*)d_in[0];
    const float* model = (const float*)d_in[1];
    const float* pred  = (const float*)d_in[2];
    const int*   gt    = (const int*)d_in[3];
    float* out = (float*)d_out;
    char*  ws  = (char*)d_ws;

    prep_kernel<<<256, 256, 0, stream>>>(inst, model, ws);
    chamfer_pass1<<<1024, 256, 0, stream>>>(
        ws + BIMG_OFF, ws + AIMG_OFF, (float*)(ws + PMIN_OFF));
    combine_kernel<<<512, 256, 0, stream>>>(
        (const float*)(ws + PMIN_OFF), (float*)(ws + PART_OFF));
    finalize_kernel<<<1, 256, 0, stream>>>(
        (const float*)(ws + PART_OFF), pred, gt, out);
}